// Round 11
// baseline (637.554 us; speedup 1.0000x reference)
//
#include <hip/hip_runtime.h>

typedef _Float16 f16;
typedef _Float16 f16x4 __attribute__((ext_vector_type(4)));
typedef _Float16 f16x8 __attribute__((ext_vector_type(8)));
typedef float f32x4 __attribute__((ext_vector_type(4)));
typedef int i32x4 __attribute__((ext_vector_type(4)));

#define ALPHA 0.2f
#define NN 8192
#define DD 256
#define INVLN2 1.44269504088896f
#define MFMA16(a, b, c) __builtin_amdgcn_mfma_f32_16x16x32_f16(a, b, c, 0, 0, 0)

// ---------------- K0: prep — WT=f16(W^T), r1/r2, zero S + maxkey ----------------
__global__ __launch_bounds__(256) void k0_prep(const float* __restrict__ W,
                                               const float* __restrict__ a,
                                               f16* __restrict__ WT,
                                               float* __restrict__ r1,
                                               float* __restrict__ r2,
                                               float* __restrict__ S,
                                               unsigned* __restrict__ maxkey) {
    const int b = blockIdx.x;
    const int t = threadIdx.x;
    if (b < 16) {
        __shared__ f16 tl[16][256];
        const int k0 = b * 16;
        const int kr = t >> 4, cb = (t & 15) << 4;
        #pragma unroll
        for (int p = 0; p < 4; ++p) {
            float4 v = *(const float4*)&W[(k0 + kr) * DD + cb + p * 4];
            tl[kr][cb + p * 4 + 0] = (f16)v.x;
            tl[kr][cb + p * 4 + 1] = (f16)v.y;
            tl[kr][cb + p * 4 + 2] = (f16)v.z;
            tl[kr][cb + p * 4 + 3] = (f16)v.w;
        }
        __syncthreads();
        f16 outv[16];
        #pragma unroll
        for (int q = 0; q < 16; ++q) outv[q] = tl[q][t];
        *(f16x8*)&WT[t * DD + k0]     = *(f16x8*)&outv[0];
        *(f16x8*)&WT[t * DD + k0 + 8] = *(f16x8*)&outv[8];
    } else {
        __shared__ float al[256];
        al[t] = a[(b - 16) * DD + t];
        __syncthreads();
        float s = 0.f;
        for (int k = 0; k < DD; ++k) s = fmaf(W[t * DD + k], al[k], s);
        float* rr = (b == 16) ? r1 : r2;
        rr[t] = s * INVLN2;
        // zero S (two blocks x 256 thr x 16 floats = 8192) and maxkey
        f32x4 z = {0.f, 0.f, 0.f, 0.f};
        float* sp = S + (b - 16) * 4096 + t * 16;
        *(f32x4*)(sp)      = z;
        *(f32x4*)(sp + 4)  = z;
        *(f32x4*)(sp + 8)  = z;
        *(f32x4*)(sp + 12) = z;
        if (b == 16 && t == 0) *maxkey = 0u;
    }
}

// ---------------- K1: WhT = f16(h@W)^T via MFMA; wave0 also Wh1/Wh2 + maxkey ------
__global__ __launch_bounds__(256) void k1_gemm(const float* __restrict__ h,
                                               const f16* __restrict__ WT,
                                               const float* __restrict__ r1,
                                               const float* __restrict__ r2,
                                               f16* __restrict__ WhT,
                                               float* __restrict__ Wh1,
                                               float* __restrict__ Wh2,
                                               unsigned* __restrict__ maxkey) {
    const int t    = threadIdx.x;
    const int lane = t & 63;
    const int w    = t >> 6;
    const int i0   = blockIdx.x * 16;
    const int r    = lane & 15;
    const int hi   = lane >> 4;
    const int nbase = w * 64;

    f32x4 acc[4];
    #pragma unroll
    for (int nc = 0; nc < 4; ++nc) acc[nc] = (f32x4){0.f, 0.f, 0.f, 0.f};
    float s1 = 0.f, s2 = 0.f;

    const float* hrow = h + (size_t)(i0 + r) * DD;
    #pragma unroll
    for (int kt = 0; kt < 8; ++kt) {
        const int kb = kt * 32 + hi * 8;
        float4 h0 = *(const float4*)&hrow[kb];
        float4 h1 = *(const float4*)&hrow[kb + 4];
        f16x8 af;
        af[0] = (f16)h0.x; af[1] = (f16)h0.y; af[2] = (f16)h0.z; af[3] = (f16)h0.w;
        af[4] = (f16)h1.x; af[5] = (f16)h1.y; af[6] = (f16)h1.z; af[7] = (f16)h1.w;
        if (w == 0) {
            float4 ra0 = *(const float4*)&r1[kb];
            float4 ra1 = *(const float4*)&r1[kb + 4];
            float4 rb0 = *(const float4*)&r2[kb];
            float4 rb1 = *(const float4*)&r2[kb + 4];
            s1 += h0.x * ra0.x + h0.y * ra0.y + h0.z * ra0.z + h0.w * ra0.w
                + h1.x * ra1.x + h1.y * ra1.y + h1.z * ra1.z + h1.w * ra1.w;
            s2 += h0.x * rb0.x + h0.y * rb0.y + h0.z * rb0.z + h0.w * rb0.w
                + h1.x * rb1.x + h1.y * rb1.y + h1.z * rb1.z + h1.w * rb1.w;
        }
        #pragma unroll
        for (int nc = 0; nc < 4; ++nc) {
            f16x8 bf = *(const f16x8*)&WT[(nbase + nc * 16 + r) * DD + kb];
            acc[nc] = MFMA16(af, bf, acc[nc]);
        }
    }
    #pragma unroll
    for (int nc = 0; nc < 4; ++nc) {
        f16x4 o;
        o[0] = (f16)acc[nc][0]; o[1] = (f16)acc[nc][1];
        o[2] = (f16)acc[nc][2]; o[3] = (f16)acc[nc][3];
        *(f16x4*)&WhT[(size_t)(nbase + nc * 16 + r) * NN + i0 + hi * 4] = o;
    }
    if (w == 0) {
        s1 += __shfl_xor(s1, 16); s1 += __shfl_xor(s1, 32);
        s2 += __shfl_xor(s2, 16); s2 += __shfl_xor(s2, 32);
        if (lane < 16) {
            Wh1[i0 + lane] = s1;
            Wh2[i0 + lane] = s2;
            unsigned u = __float_as_uint(s2);
            u = (u & 0x80000000u) ? ~u : (u | 0x80000000u);
            atomicMax(maxkey, u);
        }
    }
}

// ---------------- K3: barrier-free fused masked softmax + PV, adj direct ----------
// grid 2048 x 128 thr (2 waves = nw 0/1). js = bid&jsmask (XCD window), itile=bid>>jshift.
// Block: 32 i-rows, n=256; wave 32i x 128n; j-steps of 64 over jrange.
// NO LDS, NO barriers. A = WhT f16x8 from L2 (consume-then-reload); B = P in-register
// from adj bits (packed in-register from last step's prefetched adj values).
__device__ __forceinline__ unsigned pack8(i32x4 a, i32x4 b) {
    return (unsigned)a.x | ((unsigned)a.y << 1) | ((unsigned)a.z << 2) | ((unsigned)a.w << 3)
         | ((unsigned)b.x << 4) | ((unsigned)b.y << 5) | ((unsigned)b.z << 6) | ((unsigned)b.w << 7);
}

__device__ __forceinline__ f16x8 pcomp8(unsigned bits, float4 q0, float4 q1,
                                        float wh1r, float m_r, float& sacc) {
    float p[8];
    float e;
    e = wh1r + q0.x; e = fmaxf(e, ALPHA * e); p[0] = (bits & 1u)   ? exp2f(e - m_r) : 0.f;
    e = wh1r + q0.y; e = fmaxf(e, ALPHA * e); p[1] = (bits & 2u)   ? exp2f(e - m_r) : 0.f;
    e = wh1r + q0.z; e = fmaxf(e, ALPHA * e); p[2] = (bits & 4u)   ? exp2f(e - m_r) : 0.f;
    e = wh1r + q0.w; e = fmaxf(e, ALPHA * e); p[3] = (bits & 8u)   ? exp2f(e - m_r) : 0.f;
    e = wh1r + q1.x; e = fmaxf(e, ALPHA * e); p[4] = (bits & 16u)  ? exp2f(e - m_r) : 0.f;
    e = wh1r + q1.y; e = fmaxf(e, ALPHA * e); p[5] = (bits & 32u)  ? exp2f(e - m_r) : 0.f;
    e = wh1r + q1.z; e = fmaxf(e, ALPHA * e); p[6] = (bits & 64u)  ? exp2f(e - m_r) : 0.f;
    e = wh1r + q1.w; e = fmaxf(e, ALPHA * e); p[7] = (bits & 128u) ? exp2f(e - m_r) : 0.f;
    sacc += ((p[0] + p[1]) + (p[2] + p[3])) + ((p[4] + p[5]) + (p[6] + p[7]));
    f16x8 pk;
    pk[0] = (f16)p[0]; pk[1] = (f16)p[1]; pk[2] = (f16)p[2]; pk[3] = (f16)p[3];
    pk[4] = (f16)p[4]; pk[5] = (f16)p[5]; pk[6] = (f16)p[6]; pk[7] = (f16)p[7];
    return pk;
}

__global__ __launch_bounds__(128, 3) void k3_attn(const int* __restrict__ adj,
                                                  const f16* __restrict__ WhT,
                                                  const float* __restrict__ Wh1,
                                                  const float* __restrict__ Wh2,
                                                  const unsigned* __restrict__ maxkey,
                                                  float* __restrict__ D,
                                                  float* __restrict__ S,
                                                  int jrange, int jsmask, int jshift) {
    const int t     = threadIdx.x;
    const int lane  = t & 63;
    const int nw    = t >> 6;
    const int js    = blockIdx.x & jsmask;
    const int itile = blockIdx.x >> jshift;
    const int i0    = itile * 32;
    const int jb0   = js * jrange;
    const int ns    = jrange >> 6;

    unsigned mk = *maxkey;
    const float maxW2 = __uint_as_float((mk & 0x80000000u) ? (mk & 0x7fffffffu) : ~mk);

    const int r   = lane & 15;
    const int hi  = lane >> 4;
    const int hi8 = hi << 3;
    const int nb  = nw * 128;

    const int ia = i0 + r;
    const float wh10 = Wh1[ia];
    const float wh11 = Wh1[ia + 16];
    float t0 = wh10 + maxW2, t1 = wh11 + maxW2;
    const float m0 = fmaxf(t0, ALPHA * t0);
    const float m1 = fmaxf(t1, ALPHA * t1);

    const int* aRow0 = adj + (size_t)ia * NN + hi8;
    const int* aRow1 = aRow0 + 16 * NN;
    const f16* wbase = WhT + (size_t)(nb + r) * NN + jb0 + hi8;

    f32x4 acc[2][8];
    #pragma unroll
    for (int ic = 0; ic < 2; ++ic)
        #pragma unroll
        for (int nc = 0; nc < 8; ++nc) acc[ic][nc] = (f32x4){0.f, 0.f, 0.f, 0.f};
    float s0 = 0.f, s1 = 0.f;

    // ---- prologue: A for (s=0,kt=0); adj bits for step 0 ----
    f16x8 A[8];
    #pragma unroll
    for (int nc = 0; nc < 8; ++nc)
        A[nc] = *(const f16x8*)(wbase + (size_t)(nc * 16) * NN);
    unsigned cb0, cb1;
    {
        i32x4 x0 = *(const i32x4*)(aRow0 + jb0);
        i32x4 x1 = *(const i32x4*)(aRow0 + jb0 + 4);
        i32x4 x2 = *(const i32x4*)(aRow0 + jb0 + 32);
        i32x4 x3 = *(const i32x4*)(aRow0 + jb0 + 36);
        i32x4 y0 = *(const i32x4*)(aRow1 + jb0);
        i32x4 y1 = *(const i32x4*)(aRow1 + jb0 + 4);
        i32x4 y2 = *(const i32x4*)(aRow1 + jb0 + 32);
        i32x4 y3 = *(const i32x4*)(aRow1 + jb0 + 36);
        cb0 = pack8(x0, x1) | (pack8(x2, x3) << 8);
        cb1 = pack8(y0, y1) | (pack8(y2, y3) << 8);
    }

    for (int s = 0; s < ns; ++s) {
        const int jb = jb0 + (s << 6);
        const bool more = (s + 1 < ns);

        // issue adj loads for step s+1 (HBM; packed at end of step)
        i32x4 x0, x1, x2, x3, y0, y1, y2, y3;
        if (more) {
            const int jn = jb + 64;
            x0 = *(const i32x4*)(aRow0 + jn);
            x1 = *(const i32x4*)(aRow0 + jn + 4);
            x2 = *(const i32x4*)(aRow0 + jn + 32);
            x3 = *(const i32x4*)(aRow0 + jn + 36);
            y0 = *(const i32x4*)(aRow1 + jn);
            y1 = *(const i32x4*)(aRow1 + jn + 4);
            y2 = *(const i32x4*)(aRow1 + jn + 32);
            y3 = *(const i32x4*)(aRow1 + jn + 36);
        }

        // ---- kt = 0 ----
        float4 q00 = *(const float4*)&Wh2[jb + hi8];
        float4 q01 = *(const float4*)&Wh2[jb + hi8 + 4];
        f16x8 B00 = pcomp8(cb0 & 255u, q00, q01, wh10, m0, s0);
        f16x8 B01 = pcomp8(cb1 & 255u, q00, q01, wh11, m1, s1);
        #pragma unroll
        for (int nc = 0; nc < 8; ++nc) {
            acc[0][nc] = MFMA16(A[nc], B00, acc[0][nc]);
            acc[1][nc] = MFMA16(A[nc], B01, acc[1][nc]);
        }
        #pragma unroll
        for (int nc = 0; nc < 8; ++nc)
            A[nc] = *(const f16x8*)(wbase + (size_t)(nc * 16) * NN + (s << 6) + 32);

        // ---- kt = 1 ----
        float4 q10 = *(const float4*)&Wh2[jb + 32 + hi8];
        float4 q11 = *(const float4*)&Wh2[jb + 32 + hi8 + 4];
        f16x8 B10 = pcomp8(cb0 >> 8, q10, q11, wh10, m0, s0);
        f16x8 B11 = pcomp8(cb1 >> 8, q10, q11, wh11, m1, s1);
        #pragma unroll
        for (int nc = 0; nc < 8; ++nc) {
            acc[0][nc] = MFMA16(A[nc], B10, acc[0][nc]);
            acc[1][nc] = MFMA16(A[nc], B11, acc[1][nc]);
        }
        if (more) {
            #pragma unroll
            for (int nc = 0; nc < 8; ++nc)
                A[nc] = *(const f16x8*)(wbase + (size_t)(nc * 16) * NN + (s << 6) + 64);
            cb0 = pack8(x0, x1) | (pack8(x2, x3) << 8);
            cb1 = pack8(y0, y1) | (pack8(y2, y3) << 8);
        }
    }

    // ---- row sums -> S (nw-duplicated; commit nw==0 only) ----
    s0 += __shfl_xor(s0, 16); s0 += __shfl_xor(s0, 32);
    s1 += __shfl_xor(s1, 16); s1 += __shfl_xor(s1, 32);
    if (nw == 0 && hi == 0) {
        atomicAdd(&S[ia], s0);
        atomicAdd(&S[ia + 16], s1);
    }

    // ---- partial D -> private slab js (n = nb + nc*16 + hi*4 + q; i = ia + ic*16) ----
    float* Dp = D + (size_t)js * NN * DD + (size_t)ia * DD + nb + hi * 4;
    #pragma unroll
    for (int ic = 0; ic < 2; ++ic)
        #pragma unroll
        for (int nc = 0; nc < 8; ++nc)
            __builtin_nontemporal_store(acc[ic][nc],
                (f32x4*)(Dp + (size_t)ic * 16 * DD + nc * 16));
}

// ---------------- K4: sum slabs + normalize + ELU ----------------
__global__ __launch_bounds__(256) void k4_finish(const float* __restrict__ D,
                                                 const float* __restrict__ S,
                                                 float* __restrict__ out,
                                                 int nslab) {
    const int g   = blockIdx.x * 256 + threadIdx.x;
    const int rw  = g >> 6;
    const int c4  = (g & 63) << 2;
    const size_t off = ((size_t)rw << 8) + c4;
    f32x4 v = {0.f, 0.f, 0.f, 0.f};
    for (int s = 0; s < nslab; ++s)
        v += __builtin_nontemporal_load((const f32x4*)&D[off + (size_t)s * NN * DD]);
    const float inv = 1.0f / S[rw];
    f32x4 o;
    #pragma unroll
    for (int q = 0; q < 4; ++q) {
        float x = v[q] * inv;
        o[q] = (x > 0.f) ? x : (__expf(x) - 1.f);
    }
    *(f32x4*)&out[off] = o;
}

extern "C" void kernel_launch(void* const* d_in, const int* in_sizes, int n_in,
                              void* d_out, int out_size, void* d_ws, size_t ws_size,
                              hipStream_t stream) {
    const float* h   = (const float*)d_in[0];
    const int*   adj = (const int*)d_in[1];
    const float* W   = (const float*)d_in[2];
    const float* a   = (const float*)d_in[3];
    float* out = (float*)d_out;

    char* ws = (char*)d_ws;
    f16*      WT     = (f16*)ws;                        // 128 KB
    f16*      WhT    = (f16*)(ws + 131072);             // 4 MB
    float*    r1     = (float*)(ws + 4325376);          // 1 KB
    float*    r2     = (float*)(ws + 4326400);          // 1 KB
    float*    Wh1    = (float*)(ws + 4327424);          // 32 KB
    float*    Wh2    = (float*)(ws + 4360192);          // 32 KB
    unsigned* maxkey = (unsigned*)(ws + 4392960);       // 4 B (pad 256)
    float*    S      = (float*)(ws + 4393216);          // 32 KB
    float*    D      = (float*)(ws + 4425984);          // js_n x 8 MB

    const size_t base = 4425984;
    const size_t slab = (size_t)NN * DD * 4;
    int js_n = 2, jshift = 1;
    if (ws_size >= base + 8 * slab)      { js_n = 8; jshift = 3; }
    else if (ws_size >= base + 4 * slab) { js_n = 4; jshift = 2; }
    const int jrange = NN / js_n;

    k0_prep<<<dim3(18), dim3(256), 0, stream>>>(W, a, WT, r1, r2, S, maxkey);
    k1_gemm<<<dim3(512), dim3(256), 0, stream>>>(h, WT, r1, r2, WhT, Wh1, Wh2, maxkey);
    k3_attn<<<dim3(js_n * 256), dim3(128), 0, stream>>>(adj, WhT, Wh1, Wh2, maxkey,
                                                        D, S, jrange, js_n - 1, jshift);
    k4_finish<<<dim3(2048), dim3(256), 0, stream>>>(D, S, out, js_n);
}

// Round 12
// 201.203 us; speedup vs baseline: 3.1687x; 3.1687x over previous
//
#include <hip/hip_runtime.h>

typedef _Float16 f16;
typedef _Float16 f16x4 __attribute__((ext_vector_type(4)));
typedef _Float16 f16x8 __attribute__((ext_vector_type(8)));
typedef float f32x4 __attribute__((ext_vector_type(4)));
typedef int i32x4 __attribute__((ext_vector_type(4)));

#define ALPHA 0.2f
#define NN 8192
#define DD 256
#define INVLN2 1.44269504088896f
#define MFMA16(a, b, c) __builtin_amdgcn_mfma_f32_16x16x32_f16(a, b, c, 0, 0, 0)

// ---------------- K0: prep — WT=f16(W^T), r1/r2, zero S + maxkey ----------------
__global__ __launch_bounds__(256) void k0_prep(const float* __restrict__ W,
                                               const float* __restrict__ a,
                                               f16* __restrict__ WT,
                                               float* __restrict__ r1,
                                               float* __restrict__ r2,
                                               float* __restrict__ S,
                                               unsigned* __restrict__ maxkey) {
    const int b = blockIdx.x;
    const int t = threadIdx.x;
    if (b < 16) {
        __shared__ f16 tl[16][256];
        const int k0 = b * 16;
        const int kr = t >> 4, cb = (t & 15) << 4;
        #pragma unroll
        for (int p = 0; p < 4; ++p) {
            float4 v = *(const float4*)&W[(k0 + kr) * DD + cb + p * 4];
            tl[kr][cb + p * 4 + 0] = (f16)v.x;
            tl[kr][cb + p * 4 + 1] = (f16)v.y;
            tl[kr][cb + p * 4 + 2] = (f16)v.z;
            tl[kr][cb + p * 4 + 3] = (f16)v.w;
        }
        __syncthreads();
        f16 outv[16];
        #pragma unroll
        for (int q = 0; q < 16; ++q) outv[q] = tl[q][t];
        *(f16x8*)&WT[t * DD + k0]     = *(f16x8*)&outv[0];
        *(f16x8*)&WT[t * DD + k0 + 8] = *(f16x8*)&outv[8];
    } else {
        __shared__ float al[256];
        al[t] = a[(b - 16) * DD + t];
        __syncthreads();
        float s = 0.f;
        for (int k = 0; k < DD; ++k) s = fmaf(W[t * DD + k], al[k], s);
        float* rr = (b == 16) ? r1 : r2;
        rr[t] = s * INVLN2;
        f32x4 z = {0.f, 0.f, 0.f, 0.f};
        float* sp = S + (b - 16) * 4096 + t * 16;
        *(f32x4*)(sp)      = z;
        *(f32x4*)(sp + 4)  = z;
        *(f32x4*)(sp + 8)  = z;
        *(f32x4*)(sp + 12) = z;
        if (b == 16 && t == 0) *maxkey = 0u;
    }
}

// ---------------- K1: WhT = f16(h@W)^T via MFMA; wave0 also Wh1/Wh2 + maxkey ------
__global__ __launch_bounds__(256) void k1_gemm(const float* __restrict__ h,
                                               const f16* __restrict__ WT,
                                               const float* __restrict__ r1,
                                               const float* __restrict__ r2,
                                               f16* __restrict__ WhT,
                                               float* __restrict__ Wh1,
                                               float* __restrict__ Wh2,
                                               unsigned* __restrict__ maxkey) {
    const int t    = threadIdx.x;
    const int lane = t & 63;
    const int w    = t >> 6;
    const int i0   = blockIdx.x * 16;
    const int r    = lane & 15;
    const int hi   = lane >> 4;
    const int nbase = w * 64;

    f32x4 acc[4];
    #pragma unroll
    for (int nc = 0; nc < 4; ++nc) acc[nc] = (f32x4){0.f, 0.f, 0.f, 0.f};
    float s1 = 0.f, s2 = 0.f;

    const float* hrow = h + (size_t)(i0 + r) * DD;
    #pragma unroll
    for (int kt = 0; kt < 8; ++kt) {
        const int kb = kt * 32 + hi * 8;
        float4 h0 = *(const float4*)&hrow[kb];
        float4 h1 = *(const float4*)&hrow[kb + 4];
        f16x8 af;
        af[0] = (f16)h0.x; af[1] = (f16)h0.y; af[2] = (f16)h0.z; af[3] = (f16)h0.w;
        af[4] = (f16)h1.x; af[5] = (f16)h1.y; af[6] = (f16)h1.z; af[7] = (f16)h1.w;
        if (w == 0) {
            float4 ra0 = *(const float4*)&r1[kb];
            float4 ra1 = *(const float4*)&r1[kb + 4];
            float4 rb0 = *(const float4*)&r2[kb];
            float4 rb1 = *(const float4*)&r2[kb + 4];
            s1 += h0.x * ra0.x + h0.y * ra0.y + h0.z * ra0.z + h0.w * ra0.w
                + h1.x * ra1.x + h1.y * ra1.y + h1.z * ra1.z + h1.w * ra1.w;
            s2 += h0.x * rb0.x + h0.y * rb0.y + h0.z * rb0.z + h0.w * rb0.w
                + h1.x * rb1.x + h1.y * rb1.y + h1.z * rb1.z + h1.w * rb1.w;
        }
        #pragma unroll
        for (int nc = 0; nc < 4; ++nc) {
            f16x8 bf = *(const f16x8*)&WT[(nbase + nc * 16 + r) * DD + kb];
            acc[nc] = MFMA16(af, bf, acc[nc]);
        }
    }
    #pragma unroll
    for (int nc = 0; nc < 4; ++nc) {
        f16x4 o;
        o[0] = (f16)acc[nc][0]; o[1] = (f16)acc[nc][1];
        o[2] = (f16)acc[nc][2]; o[3] = (f16)acc[nc][3];
        *(f16x4*)&WhT[(size_t)(nbase + nc * 16 + r) * NN + i0 + hi * 4] = o;
    }
    if (w == 0) {
        s1 += __shfl_xor(s1, 16); s1 += __shfl_xor(s1, 32);
        s2 += __shfl_xor(s2, 16); s2 += __shfl_xor(s2, 32);
        if (lane < 16) {
            Wh1[i0 + lane] = s1;
            Wh2[i0 + lane] = s2;
            unsigned u = __float_as_uint(s2);
            u = (u & 0x80000000u) ? ~u : (u | 0x80000000u);
            atomicMax(maxkey, u);
        }
    }
}

// ---------------- K3: fused masked softmax + PV ----------------
// grid = 256 itiles x js_n blocks, 256 thr (4 waves). js = bid & jsmask (XCD-aligned
// j-window), itile = bid >> jshift. Block: 32 i-rows, full n=256, j-steps of 64.
// P computed ONCE (all 256 threads, row=t>>3, jc=t&7) -> 4KB XOR-swizzled LDS dbuf.
// Wave w: n in [w*64, w*64+64); A = P-frags from LDS; B = WhT f16x8 from L2.
// ALL long-latency loads (adj s+2, B both kt) issued at TOP of step so the
// end-of-step barrier's vmcnt(0) drain waits on already-aged loads.
__device__ __forceinline__ f16x8 pcomp8(i32x4 a0, i32x4 a1, float4 q0, float4 q1,
                                        float wh1r, float m_r, float& sacc) {
    float p[8];
    float e;
    e = wh1r + q0.x; e = fmaxf(e, ALPHA * e); p[0] = (a0.x > 0) ? exp2f(e - m_r) : 0.f;
    e = wh1r + q0.y; e = fmaxf(e, ALPHA * e); p[1] = (a0.y > 0) ? exp2f(e - m_r) : 0.f;
    e = wh1r + q0.z; e = fmaxf(e, ALPHA * e); p[2] = (a0.z > 0) ? exp2f(e - m_r) : 0.f;
    e = wh1r + q0.w; e = fmaxf(e, ALPHA * e); p[3] = (a0.w > 0) ? exp2f(e - m_r) : 0.f;
    e = wh1r + q1.x; e = fmaxf(e, ALPHA * e); p[4] = (a1.x > 0) ? exp2f(e - m_r) : 0.f;
    e = wh1r + q1.y; e = fmaxf(e, ALPHA * e); p[5] = (a1.y > 0) ? exp2f(e - m_r) : 0.f;
    e = wh1r + q1.z; e = fmaxf(e, ALPHA * e); p[6] = (a1.z > 0) ? exp2f(e - m_r) : 0.f;
    e = wh1r + q1.w; e = fmaxf(e, ALPHA * e); p[7] = (a1.w > 0) ? exp2f(e - m_r) : 0.f;
    sacc += ((p[0] + p[1]) + (p[2] + p[3])) + ((p[4] + p[5]) + (p[6] + p[7]));
    f16x8 pk;
    pk[0] = (f16)p[0]; pk[1] = (f16)p[1]; pk[2] = (f16)p[2]; pk[3] = (f16)p[3];
    pk[4] = (f16)p[4]; pk[5] = (f16)p[5]; pk[6] = (f16)p[6]; pk[7] = (f16)p[7];
    return pk;
}

__global__ __launch_bounds__(256, 3) void k3_attn(const int* __restrict__ adj,
                                                  const f16* __restrict__ WhT,
                                                  const float* __restrict__ Wh1,
                                                  const float* __restrict__ Wh2,
                                                  const unsigned* __restrict__ maxkey,
                                                  float* __restrict__ D,
                                                  float* __restrict__ S,
                                                  int jrange, int jsmask, int jshift) {
    __shared__ __align__(16) f16 pbuf[2][32 * 64];    // 2 x 4 KB

    const int t     = threadIdx.x;
    const int lane  = t & 63;
    const int w     = t >> 6;
    const int js    = blockIdx.x & jsmask;
    const int itile = blockIdx.x >> jshift;
    const int i0    = itile * 32;
    const int jb0   = js * jrange;
    const int ns    = jrange >> 6;

    unsigned mk = *maxkey;
    const float maxW2 = __uint_as_float((mk & 0x80000000u) ? (mk & 0x7fffffffu) : ~mk);

    // phase-A role: row (0..31), jc (8 j's per step)
    const int row = t >> 3;
    const int jc  = t & 7;
    const float wh1r = Wh1[i0 + row];
    float tm = wh1r + maxW2;
    const float m_r = fmaxf(tm, ALPHA * tm);
    const int*   aRow = adj + (size_t)(i0 + row) * NN + jc * 8;
    const float* w2p  = Wh2 + jc * 8;
    const int pwb = row * 128 + ((jc ^ (row & 7)) << 4);

    // phase-B role
    const int r  = lane & 63 & 15;
    const int hi = lane >> 4;
    const int nb = w * 64;
    const int rx = (r & 7) << 4;
    const f16* wbase = WhT + (size_t)(nb + r) * NN + jb0 + hi * 8;

    f32x4 acc[2][4];
    #pragma unroll
    for (int ic = 0; ic < 2; ++ic)
        #pragma unroll
        for (int nc = 0; nc < 4; ++nc) acc[ic][nc] = (f32x4){0.f, 0.f, 0.f, 0.f};
    float sacc = 0.f;

    // ---- prologue: P(0) -> pbuf[0]; issue adj(1) ----
    {
        i32x4 a0 = *(const i32x4*)(aRow + jb0);
        i32x4 a1 = *(const i32x4*)(aRow + jb0 + 4);
        float4 q0 = *(const float4*)(w2p + jb0);
        float4 q1 = *(const float4*)(w2p + jb0 + 4);
        f16x8 pk = pcomp8(a0, a1, q0, q1, wh1r, m_r, sacc);
        *(f16x8*)((char*)pbuf[0] + pwb) = pk;
    }
    i32x4 aU0, aU1;
    if (ns > 1) {
        aU0 = *(const i32x4*)(aRow + jb0 + 64);
        aU1 = *(const i32x4*)(aRow + jb0 + 68);
    }
    __syncthreads();

    for (int s = 0; s < ns; ++s) {
        const int sel = s & 1;
        const int jb  = jb0 + (s << 6);
        const bool more = (s + 1 < ns);

        // (1) TOP: issue adj(s+2) into aV — ages a full step before any drain
        i32x4 aV0, aV1;
        if (s + 2 < ns) {
            aV0 = *(const i32x4*)(aRow + jb + 128);
            aV1 = *(const i32x4*)(aRow + jb + 132);
        }
        // (2) issue B(WhT) loads for BOTH kt of this step (L2)
        f16x8 B[2][4];
        #pragma unroll
        for (int kt = 0; kt < 2; ++kt)
            #pragma unroll
            for (int nc = 0; nc < 4; ++nc)
                B[kt][nc] = *(const f16x8*)(wbase + (size_t)(nc * 16) * NN
                                            + (s << 6) + kt * 32);
        // (3) A(P) fragments from LDS
        f16x8 A[2][2];
        #pragma unroll
        for (int kt = 0; kt < 2; ++kt) {
            const int kb = (((kt * 4 + hi) << 4) ^ rx);
            A[kt][0] = *(const f16x8*)((const char*)pbuf[sel] + r * 128 + kb);
            A[kt][1] = *(const f16x8*)((const char*)pbuf[sel] + (16 + r) * 128 + kb);
        }
        // (4) compute P(s+1) from aU (VALU covers the B-load latency), write LDS
        if (more) {
            const int jn = jb + 64;
            float4 q0 = *(const float4*)(w2p + jn);
            float4 q1 = *(const float4*)(w2p + jn + 4);
            f16x8 pk = pcomp8(aU0, aU1, q0, q1, wh1r, m_r, sacc);
            *(f16x8*)((char*)pbuf[sel ^ 1] + pwb) = pk;
            aU0 = aV0; aU1 = aV1;
        }
        // (5) MFMA
        #pragma unroll
        for (int kt = 0; kt < 2; ++kt) {
            acc[0][0] = MFMA16(A[kt][0], B[kt][0], acc[0][0]);
            acc[0][1] = MFMA16(A[kt][0], B[kt][1], acc[0][1]);
            acc[0][2] = MFMA16(A[kt][0], B[kt][2], acc[0][2]);
            acc[0][3] = MFMA16(A[kt][0], B[kt][3], acc[0][3]);
            acc[1][0] = MFMA16(A[kt][1], B[kt][0], acc[1][0]);
            acc[1][1] = MFMA16(A[kt][1], B[kt][1], acc[1][1]);
            acc[1][2] = MFMA16(A[kt][1], B[kt][2], acc[1][2]);
            acc[1][3] = MFMA16(A[kt][1], B[kt][3], acc[1][3]);
        }
        __syncthreads();
    }

    // ---- row sums -> S (8 consecutive threads per row) ----
    sacc += __shfl_xor(sacc, 1);
    sacc += __shfl_xor(sacc, 2);
    sacc += __shfl_xor(sacc, 4);
    if ((t & 7) == 0) atomicAdd(&S[i0 + row], sacc);

    // ---- partial D -> private slab js: i = i0 + ic*16 + hi*4 + q, n = nb + nc*16 + r ----
    float* Dp = D + (size_t)js * NN * DD + (size_t)(i0 + hi * 4) * DD + nb + r;
    #pragma unroll
    for (int ic = 0; ic < 2; ++ic)
        #pragma unroll
        for (int nc = 0; nc < 4; ++nc)
            #pragma unroll
            for (int q = 0; q < 4; ++q)
                __builtin_nontemporal_store(acc[ic][nc][q],
                                            Dp + (size_t)(ic * 16 + q) * DD + nc * 16);
}

// ---------------- K4: sum slabs + normalize + ELU ----------------
__global__ __launch_bounds__(256) void k4_finish(const float* __restrict__ D,
                                                 const float* __restrict__ S,
                                                 float* __restrict__ out,
                                                 int nslab) {
    const int g   = blockIdx.x * 256 + threadIdx.x;
    const int rw  = g >> 6;
    const int c4  = (g & 63) << 2;
    const size_t off = ((size_t)rw << 8) + c4;
    f32x4 v = {0.f, 0.f, 0.f, 0.f};
    for (int s = 0; s < nslab; ++s)
        v += __builtin_nontemporal_load((const f32x4*)&D[off + (size_t)s * NN * DD]);
    const float inv = 1.0f / S[rw];
    f32x4 o;
    #pragma unroll
    for (int q = 0; q < 4; ++q) {
        float x = v[q] * inv;
        o[q] = (x > 0.f) ? x : (__expf(x) - 1.f);
    }
    *(f32x4*)&out[off] = o;
}

extern "C" void kernel_launch(void* const* d_in, const int* in_sizes, int n_in,
                              void* d_out, int out_size, void* d_ws, size_t ws_size,
                              hipStream_t stream) {
    const float* h   = (const float*)d_in[0];
    const int*   adj = (const int*)d_in[1];
    const float* W   = (const float*)d_in[2];
    const float* a   = (const float*)d_in[3];
    float* out = (float*)d_out;

    char* ws = (char*)d_ws;
    f16*      WT     = (f16*)ws;                        // 128 KB
    f16*      WhT    = (f16*)(ws + 131072);             // 4 MB
    float*    r1     = (float*)(ws + 4325376);          // 1 KB
    float*    r2     = (float*)(ws + 4326400);          // 1 KB
    float*    Wh1    = (float*)(ws + 4327424);          // 32 KB
    float*    Wh2    = (float*)(ws + 4360192);          // 32 KB
    unsigned* maxkey = (unsigned*)(ws + 4392960);       // 4 B (pad 256)
    float*    S      = (float*)(ws + 4393216);          // 32 KB
    float*    D      = (float*)(ws + 4425984);          // js_n x 8 MB

    const size_t base = 4425984;
    const size_t slab = (size_t)NN * DD * 4;
    int js_n = 2, jshift = 1;
    if (ws_size >= base + 8 * slab)      { js_n = 8; jshift = 3; }
    else if (ws_size >= base + 4 * slab) { js_n = 4; jshift = 2; }
    const int jrange = NN / js_n;

    k0_prep<<<dim3(18), dim3(256), 0, stream>>>(W, a, WT, r1, r2, S, maxkey);
    k1_gemm<<<dim3(512), dim3(256), 0, stream>>>(h, WT, r1, r2, WhT, Wh1, Wh2, maxkey);
    k3_attn<<<dim3(js_n * 256), dim3(256), 0, stream>>>(adj, WhT, Wh1, Wh2, maxkey,
                                                        D, S, jrange, js_n - 1, jshift);
    k4_finish<<<dim3(2048), dim3(256), 0, stream>>>(D, S, out, js_n);
}